// Round 11
// baseline (123.247 us; speedup 1.0000x reference)
//
#include <hip/hip_runtime.h>
#include <hip/hip_bf16.h>
#include <math.h>

#define N_NODES 10000
#define N_EDGES 160000
#define DIN 128
#define DW 512
#define NHEAD 8
#define NC 64
#define MPAD 10112     // 79 * 128
#define GEMM_BLKS 316  // 79 * 4

typedef unsigned short ushort_t;
typedef __attribute__((ext_vector_type(8))) short bf16x8;
typedef __attribute__((ext_vector_type(8))) unsigned short us8;
typedef __attribute__((ext_vector_type(4))) float f32x4;
typedef __attribute__((ext_vector_type(2))) unsigned int u32x2;

__device__ inline ushort_t f2bf(float v) {
    unsigned u = __builtin_bit_cast(unsigned, v);
    return (ushort_t)((u + 0x7fff + ((u >> 16) & 1)) >> 16);
}
__device__ inline float bf2f(ushort_t h) {
    return __builtin_bit_cast(float, (unsigned)h << 16);
}

// swizzled tile-major index: tiles of 128 rows x 64 k, 8192 ushort each.
__device__ __forceinline__ size_t swz_idx(int rb, int r, int kp, int nkt) {
    int kt = kp >> 6, kc = kp & 63;
    return ((size_t)(rb * nkt + kt)) * 8192 + r * 64 + (kc ^ ((r & 7) << 3));
}

__device__ __forceinline__ void gld16(const ushort_t* g, ushort_t* l) {
    __builtin_amdgcn_global_load_lds(
        (const __attribute__((address_space(1))) void*)g,
        (__attribute__((address_space(3))) void*)l, 16, 0, 0);
}

// ================= merged prep: prepx(vec) + prepWft + prepW1 + zero =================
__global__ void k_prep(const float* __restrict__ x, const float* __restrict__ ftW,
                       const float* __restrict__ W1f,
                       ushort_t* __restrict__ Ax, ushort_t* __restrict__ Bx,
                       ushort_t* __restrict__ B1,
                       int* __restrict__ cnt, int* __restrict__ cursor) {
    int bid = blockIdx.x, t = threadIdx.x;
    if (bid < 632) {                        // prepx: Ax[MPAD][256] = [xhi | xlo], 16B stores
        int gid = bid * 256 + t;            // n * 16 + chunk
        int n = gid >> 4, k0 = (gid & 15) * 8;
        float v[8];
        if (n < N_NODES) {
            #pragma unroll
            for (int u = 0; u < 8; u++) v[u] = x[n * DIN + k0 + u];
        } else {
            #pragma unroll
            for (int u = 0; u < 8; u++) v[u] = 0.f;
        }
        us8 hi, lo;
        #pragma unroll
        for (int u = 0; u < 8; u++) {
            ushort_t h = f2bf(v[u]);
            hi[u] = h;
            lo[u] = f2bf(v[u] - bf2f(h));
        }
        int rb = n >> 7, r = n & 127;
        *(us8*)(Ax + swz_idx(rb, r, k0, 4)) = hi;
        *(us8*)(Ax + swz_idx(rb, r, 128 + k0, 4)) = lo;
    } else if (bid < 888) {                 // prepWft: Bx[512][256] = [Whi | Whi]
        int i = (bid - 632) * 256 + t;
        int n = i >> 7, k = i & 127;
        ushort_t h = f2bf(ftW[k * DW + n]);
        int cb = n >> 7, rc = n & 127;
        Bx[swz_idx(cb, rc, k, 4)] = h;
        Bx[swz_idx(cb, rc, 128 + k, 4)] = h;
    } else if (bid < 1912) {                // prepW1: B1[512][1024] = [W1hi | W1hi]
        int i = (bid - 888) * 256 + t;
        int n = i >> 9, k = i & 511;
        ushort_t h = f2bf(W1f[k * DW + n]);
        int cb = n >> 7, rc = n & 127;
        B1[swz_idx(cb, rc, k, 16)] = h;
        B1[swz_idx(cb, rc, 512 + k, 16)] = h;
    } else {                                // zero cnt/cursor
        int i = (bid - 1912) * 256 + t;
        if (i < N_NODES) { cnt[i] = 0; cursor[i] = 0; }
    }
}

// ================= LDS-DMA double-buffered bf16 MFMA GEMM, 8 waves (+side work) =================
// C = A[MPAD][KT*64] @ B[512][KT*64]^T ; pre-swizzled tile-major operands.
// 128x128 tile, 512 threads: wave = 32 rows x 64 cols (acc[2][4]).
// EXTRA: 1 = CSR count, 2 = CSR scatter (blocks >= GEMM_BLKS).
template<int KT, bool ATT, int EXTRA>
__global__ __launch_bounds__(512, 4) void k_tgemm(const ushort_t* __restrict__ A,
                                                  const ushort_t* __restrict__ Bm,
                                                  float* __restrict__ C,
                                                  ushort_t* __restrict__ Cb,
                                                  const float* __restrict__ asrc,
                                                  const float* __restrict__ adst,
                                                  float* __restrict__ aS,
                                                  float* __restrict__ aD,
                                                  const int* __restrict__ ei,
                                                  int* __restrict__ cnt,
                                                  const int* __restrict__ off,
                                                  int* __restrict__ cursor,
                                                  int* __restrict__ csrc) {
    __shared__ __align__(16) ushort_t As[2][8192];
    __shared__ __align__(16) ushort_t Bs[2][8192];
    int bid = blockIdx.x;
    if (bid >= GEMM_BLKS) {                 // ---- CSR side work ----
        int e = (bid - GEMM_BLKS) * 512 + threadIdx.x;
        if (e < N_EDGES) {
            if (EXTRA == 1) {
                atomicAdd(&cnt[ei[N_EDGES + e]], 1);
            } else {
                int d = ei[N_EDGES + e];
                int p = off[d] + atomicAdd(&cursor[d], 1);
                csrc[p] = ei[e];
            }
        }
        return;
    }
    int bx = bid >> 2, by = bid & 3;
    int t = threadIdx.x, w = t >> 6, l = t & 63;
    int lm = l & 15, g = l >> 4;
    int wr = w >> 1, wc = w & 1;            // 4 row-stripes x 2 col-stripes
    int rowbase = bx * 128;
    int colbase = by * 128;

    const ushort_t* Abase = A + (size_t)bx * KT * 8192 + t * 8;
    const ushort_t* Bbase = Bm + (size_t)by * KT * 8192 + t * 8;

    f32x4 acc[2][4];
    #pragma unroll
    for (int r = 0; r < 2; r++)
        #pragma unroll
        for (int c = 0; c < 4; c++) acc[r][c] = (f32x4){0.f, 0.f, 0.f, 0.f};

    {   // prologue: tile 0 -> buf 0 (4 DMA/thread)
        #pragma unroll
        for (int j = 0; j < 2; ++j) {
            gld16(Abase + j * 4096, &As[0][j * 4096 + t * 8]);
            gld16(Bbase + j * 4096, &Bs[0][j * 4096 + t * 8]);
        }
    }

    int p = 0;
    for (int kt = 0; kt < KT; ++kt) {
        __builtin_amdgcn_s_barrier();       // all waves done reading buf[p^1]
        if (kt + 1 < KT) {
            const ushort_t* ga = Abase + (size_t)(kt + 1) * 8192;
            const ushort_t* gb = Bbase + (size_t)(kt + 1) * 8192;
            #pragma unroll
            for (int j = 0; j < 2; ++j) {
                gld16(ga + j * 4096, &As[p ^ 1][j * 4096 + t * 8]);
                gld16(gb + j * 4096, &Bs[p ^ 1][j * 4096 + t * 8]);
            }
            asm volatile("s_waitcnt vmcnt(4)" ::: "memory");   // tile kt landed
        } else {
            asm volatile("s_waitcnt vmcnt(0)" ::: "memory");
        }
        __builtin_amdgcn_s_barrier();       // ALL waves' tile-kt DMA complete
        const char* Ap = (const char*)As[p];
        const char* Bp = (const char*)Bs[p];
        #pragma unroll
        for (int ks = 0; ks < 2; ++ks) {
            bf16x8 af[2], bfr[4];
            #pragma unroll
            for (int r = 0; r < 2; ++r) {
                int row = wr * 32 + r * 16 + lm;
                af[r] = *(const bf16x8*)(Ap + row * 128 +
                                         ((ks * 64 + g * 16) ^ ((row & 7) << 4)));
            }
            #pragma unroll
            for (int c = 0; c < 4; ++c) {
                int col = wc * 64 + c * 16 + lm;
                bfr[c] = *(const bf16x8*)(Bp + col * 128 +
                                          ((ks * 64 + g * 16) ^ ((col & 7) << 4)));
            }
            #pragma unroll
            for (int r = 0; r < 2; ++r)
                #pragma unroll
                for (int c = 0; c < 4; ++c)
                    acc[r][c] = __builtin_amdgcn_mfma_f32_16x16x32_bf16(af[r], bfr[c], acc[r][c], 0, 0, 0);
        }
        p ^= 1;
    }

    // C/D map: col = lane&15, row = (lane>>4)*4 + q
    if (!ATT) {
        #pragma unroll
        for (int r = 0; r < 2; ++r) {
            int row0 = rowbase + wr * 32 + r * 16 + g * 4;
            #pragma unroll
            for (int c = 0; c < 4; ++c) {
                int col = colbase + wc * 64 + c * 16 + lm;
                #pragma unroll
                for (int q = 0; q < 4; ++q)
                    if (row0 + q < N_NODES) C[(size_t)(row0 + q) * DW + col] = acc[r][c][q];
            }
        }
    } else {
        int h = 2 * by + wc;                  // this wave's head
        float asv[4], adv[4];
        #pragma unroll
        for (int c = 0; c < 4; ++c) {
            asv[c] = asrc[h * NC + c * 16 + lm];
            adv[c] = adst[h * NC + c * 16 + lm];
        }
        #pragma unroll
        for (int r = 0; r < 2; ++r) {
            int row0 = rowbase + wr * 32 + r * 16 + g * 4;
            #pragma unroll
            for (int c = 0; c < 4; ++c) {
                int col = colbase + wc * 64 + c * 16 + lm;
                #pragma unroll
                for (int q = 0; q < 4; ++q)
                    if (row0 + q < N_NODES) Cb[(size_t)(row0 + q) * DW + col] = f2bf(acc[r][c][q]);
            }
            #pragma unroll
            for (int q = 0; q < 4; ++q) {
                float ss = acc[r][0][q] * asv[0] + acc[r][1][q] * asv[1] +
                           acc[r][2][q] * asv[2] + acc[r][3][q] * asv[3];
                float dd = acc[r][0][q] * adv[0] + acc[r][1][q] * adv[1] +
                           acc[r][2][q] * adv[2] + acc[r][3][q] * adv[3];
                #pragma unroll
                for (int m = 1; m < 16; m <<= 1) {
                    ss += __shfl_xor(ss, m, 64);
                    dd += __shfl_xor(dd, m, 64);
                }
                int row = row0 + q;
                if (lm == 0 && row < N_NODES) {
                    aS[row * NHEAD + h] = ss;
                    aD[row * NHEAD + h] = dd;
                }
            }
        }
    }
}

// ================= LN epilogue -> h0big[*][1024] = [hi | lo], vectorized (+ scan block) =================
__global__ __launch_bounds__(256) void k_ln_scan(const float* __restrict__ hpre,
                                                 const float* __restrict__ fb,
                                                 const float* __restrict__ g,
                                                 const float* __restrict__ beta,
                                                 ushort_t* __restrict__ h0big,
                                                 const int* __restrict__ cnt,
                                                 int* __restrict__ off) {
    __shared__ int ps[256];
    __shared__ float red[8];
    __shared__ __align__(16) ushort_t st[1024];
    int bid = blockIdx.x, t = threadIdx.x;
    if (bid == MPAD) {                       // ---- exclusive scan over cnt ----
        int base = t * 40;
        int loc[40];
        int s = 0;
        #pragma unroll
        for (int i = 0; i < 40; i++) {
            int idx = base + i;
            int v = idx < N_NODES ? cnt[idx] : 0;
            loc[i] = s; s += v;
        }
        ps[t] = s; __syncthreads();
        for (int o = 1; o < 256; o <<= 1) {
            int v = (t >= o) ? ps[t - o] : 0;
            __syncthreads();
            ps[t] += v;
            __syncthreads();
        }
        int pre = (t > 0) ? ps[t - 1] : 0;
        #pragma unroll
        for (int i = 0; i < 40; i++) {
            int idx = base + i;
            if (idx < N_NODES) off[idx] = pre + loc[i];
        }
        if (t == 255) off[N_NODES] = ps[255];
        return;
    }
    int n = bid;
    int rb = n >> 7, r = n & 127;
    if (n >= N_NODES) {
        if (t < 128) {
            int kp0 = t * 8;
            *(us8*)(h0big + swz_idx(rb, r, kp0, 16)) = (us8){0,0,0,0,0,0,0,0};
        }
        return;
    }
    float a0 = hpre[(size_t)n * DW + t] + fb[t];
    float a1 = hpre[(size_t)n * DW + t + 256] + fb[t + 256];
    float s = a0 + a1, sq = a0 * a0 + a1 * a1;
    for (int o = 32; o > 0; o >>= 1) { s += __shfl_down(s, o, 64); sq += __shfl_down(sq, o, 64); }
    int wid = t >> 6;
    if ((t & 63) == 0) { red[wid] = s; red[4 + wid] = sq; }
    __syncthreads();
    if (t == 0) {
        float ts = red[0] + red[1] + red[2] + red[3];
        float tq = red[4] + red[5] + red[6] + red[7];
        float mu = ts / DW;
        float var = tq / DW - mu * mu;
        red[0] = mu; red[1] = rsqrtf(var + 1e-5f);
    }
    __syncthreads();
    float mu = red[0], rs = red[1];
    float v0 = (a0 - mu) * rs * g[t] + beta[t];
    float v1 = (a1 - mu) * rs * g[t + 256] + beta[t + 256];
    v0 = v0 >= 0.f ? v0 : 0.2f * v0;
    v1 = v1 >= 0.f ? v1 : 0.2f * v1;
    ushort_t h0_ = f2bf(v0), l0_ = f2bf(v0 - bf2f(h0_));
    ushort_t h1_ = f2bf(v1), l1_ = f2bf(v1 - bf2f(h1_));
    st[t] = h0_;        st[256 + t] = h1_;      // hi occupies kp 0..511
    st[512 + t] = l0_;  st[768 + t] = l1_;      // lo occupies kp 512..1023
    __syncthreads();
    if (t < 128) {
        int kp0 = t * 8;
        *(us8*)(h0big + swz_idx(rb, r, kp0, 16)) = *(const us8*)(st + kp0);
    }
}

// ================= layer-1 aggregation + BN/ReLU + GEMM2 + att2 (fused) =================
// Block n: 2 edge-groups x 128 threads, 4 cols/thread (8B gather loads) -> 2 edges
// in flight; partials combined in LDS; then h2 row -> GEMM2 -> aS2/aD2.
__global__ __launch_bounds__(256) void k_agg1g2(
    const int* __restrict__ csrc, const int* __restrict__ off,
    const ushort_t* __restrict__ h1b,
    const float* __restrict__ aS, const float* __restrict__ aD,
    const float* __restrict__ b1, const float* __restrict__ bnm,
    const float* __restrict__ bnv, const float* __restrict__ bng,
    const float* __restrict__ bnb,
    const float* __restrict__ W2, const float* __restrict__ as2,
    const float* __restrict__ ad2,
    float* __restrict__ gbuf, float* __restrict__ aS2, float* __restrict__ aD2)
{
    int n = blockIdx.x, t = threadIdx.x;
    int beg = off[n], end = off[n + 1];
    __shared__ float wls[64][NHEAD];
    __shared__ int   sls[64];
    __shared__ float aDn[NHEAD];
    __shared__ float dsum[NHEAD];
    __shared__ float h2row[DW];
    __shared__ float part[128][5];
    __shared__ float pr[16][17];
    __shared__ float gl[16];
    if (t < NHEAD) { aDn[t] = aD[n * NHEAD + t]; dsum[t] = 0.f; }
    __syncthreads();
    int grp = t >> 7, tt = t & 127;        // edge-group, lane-in-group
    int j0 = 4 * tt;                       // this thread's 4 columns
    int hA = tt >> 4;                      // head of cols j0..j0+3
    float acc[4] = {0.f, 0.f, 0.f, 0.f};
    float dpart = 0.f;
    for (int c = beg; c < end; c += 64) {
        int m = min(64, end - c);
        if (t < m) sls[t] = csrc[c + t];
        __syncthreads();
        for (int idx = t; idx < m * NHEAD; idx += 256) {
            int el = idx >> 3, h = idx & 7;
            float l = aS[sls[el] * NHEAD + h] + aDn[h];
            l = l >= 0.f ? l : 0.2f * l;
            float w = __expf(l);
            wls[el][h] = w;
            dpart += w;
        }
        __syncthreads();
        for (int el = grp; el < m; el += 2) {      // 2 edges in flight (one per group)
            float w = wls[el][hA];
            u32x2 v = *(const u32x2*)(h1b + (size_t)sls[el] * DW + j0);
            acc[0] += w * __builtin_bit_cast(float, v[0] << 16);
            acc[1] += w * __builtin_bit_cast(float, v[0] & 0xffff0000u);
            acc[2] += w * __builtin_bit_cast(float, v[1] << 16);
            acc[3] += w * __builtin_bit_cast(float, v[1] & 0xffff0000u);
        }
        __syncthreads();
    }
    // combine group partials
    if (grp) {
        part[tt][0] = acc[0]; part[tt][1] = acc[1];
        part[tt][2] = acc[2]; part[tt][3] = acc[3];
    }
    // denominator reduce (both groups contribute)
    for (int o = 8; o < 64; o <<= 1) dpart += __shfl_down(dpart, o, 64);
    if ((t & 63) < NHEAD) atomicAdd(&dsum[t & 7], dpart);
    __syncthreads();
    if (!grp) {
        float rd = dsum[hA] > 0.f ? 1.f / dsum[hA] : 0.f;
        #pragma unroll
        for (int q = 0; q < 4; q++) {
            int j = j0 + q;
            float v = (acc[q] + part[tt][q]) * rd + b1[j];
            v = (v - bnm[j]) * rsqrtf(bnv[j] + 1e-5f) * bng[j] + bnb[j];
            h2row[j] = v > 0.f ? v : 0.f;
        }
    }
    __syncthreads();
    // ---- GEMM2: g[j] = sum_k h2row[k] * W2[k][j], 16 segs x 16 cols ----
    int j = t & 15, seg = t >> 4;
    const float* wp = W2 + (seg * 32) * 16 + j;
    float partg = 0.f;
    #pragma unroll 8
    for (int k = 0; k < 32; k++) partg += h2row[seg * 32 + k] * wp[k * 16];
    pr[seg][j] = partg;
    __syncthreads();
    if (t < 16) {
        float accg = 0.f;
        #pragma unroll
        for (int s2 = 0; s2 < 16; s2++) accg += pr[s2][t];
        gl[t] = accg;
        gbuf[n * 16 + t] = accg;
    }
    __syncthreads();
    if (t < 8) {
        aS2[n * NHEAD + t] = gl[2 * t] * as2[2 * t] + gl[2 * t + 1] * as2[2 * t + 1];
    } else if (t < 16) {
        int h = t - 8;
        aD2[n * NHEAD + h] = gl[2 * h] * ad2[2 * h] + gl[2 * h + 1] * ad2[2 * h + 1];
    }
}

// ================= layer-2 aggregation, CSR, fused head-mean + b2 =================
__global__ __launch_bounds__(256) void k_agg2csr(
    const int* __restrict__ csrc, const int* __restrict__ off,
    const float* __restrict__ gbuf,
    const float* __restrict__ aS, const float* __restrict__ aD,
    const float* __restrict__ b2, float* __restrict__ outp)
{
    int t = threadIdx.x;
    int n = blockIdx.x * 4 + (t >> 6);
    int lane = t & 63;
    if (n >= N_NODES) return;
    int beg = off[n], end = off[n + 1];
    int j = lane & 15, slot = lane >> 4, h = j >> 1;
    float adn = aD[n * NHEAD + h];
    float acc = 0.f, den = 0.f;
    for (int c = beg + slot; c < end; c += 4) {
        int s = csrc[c];
        float l = aS[s * NHEAD + h] + adn;
        l = l >= 0.f ? l : 0.2f * l;
        float w = __expf(l);
        den += w;
        acc += w * gbuf[s * 16 + j];
    }
    acc += __shfl_down(acc, 16, 64); acc += __shfl_down(acc, 32, 64);
    den += __shfl_down(den, 16, 64); den += __shfl_down(den, 32, 64);
    float v = (lane < 16 && den > 0.f) ? acc / den : 0.f;
    v += __shfl_down(v, 2, 64);
    v += __shfl_down(v, 4, 64);
    v += __shfl_down(v, 8, 64);
    if (lane < 2) outp[n * 2 + lane] = v * 0.125f + b2[lane];
}

extern "C" void kernel_launch(void* const* d_in, const int* in_sizes, int n_in,
                              void* d_out, int out_size, void* d_ws, size_t ws_size,
                              hipStream_t stream) {
    const float* x    = (const float*)d_in[0];
    const int*   ei   = (const int*)d_in[1];
    const float* ftW  = (const float*)d_in[2];
    const float* ftb  = (const float*)d_in[3];
    const float* lng  = (const float*)d_in[4];
    const float* lnb  = (const float*)d_in[5];
    const float* W1   = (const float*)d_in[6];
    const float* as1  = (const float*)d_in[7];
    const float* ad1  = (const float*)d_in[8];
    const float* b1   = (const float*)d_in[9];
    const float* bng  = (const float*)d_in[10];
    const float* bnb  = (const float*)d_in[11];
    const float* bnm  = (const float*)d_in[12];
    const float* bnv  = (const float*)d_in[13];
    const float* W2   = (const float*)d_in[14];
    const float* as2  = (const float*)d_in[15];
    const float* ad2  = (const float*)d_in[16];
    const float* b2   = (const float*)d_in[17];
    float* out = (float*)d_out;

    // ---- workspace (float offsets), lifetime-aliased, ~60.2 MB ----
    float* F = (float*)d_ws;
    ushort_t* Ax    = (ushort_t*)(F + 0);          // 1,294,336 f (dead after ft GEMM)
    float*    gbuf  = F + 0;                       // 160,000 f
    ushort_t* Bx    = (ushort_t*)(F + 1294336);    // 65,536 f
    ushort_t* B1    = (ushort_t*)(F + 1359872);    // 262,144 f
    float*    hpre  = F + 1622016;                 // 5,177,344 f (dead after LN)
    ushort_t* h0big = (ushort_t*)(F + 6799360);    // 5,177,344 f
    ushort_t* h1b   = (ushort_t*)(F + 11976704);   // 2,560,000 f
    float*    aS1   = F + 14536704;                // 80,000
    float*    aD1   = F + 14616704;                // 80,000
    float*    aS2   = F + 14696704;                // 80,000
    float*    aD2   = F + 14776704;                // 80,000
    int* cnt        = (int*)(F + 14856704);
    int* cursor     = (int*)(F + 14866704);
    int* off        = (int*)(F + 14876704);
    int* csrc       = (int*)(F + 14886705);        // -> end 15,046,705 f

    // 1. merged prep (Ax-vec + Bx + B1 + zero)
    k_prep<<<1952, 256, 0, stream>>>(x, ftW, W1, Ax, Bx, B1, cnt, cursor);
    // 2. ft GEMM (K'=256) + CSR count
    k_tgemm<4, false, 1><<<GEMM_BLKS + 313, 512, 0, stream>>>(
        Ax, Bx, hpre, nullptr, nullptr, nullptr, nullptr, nullptr,
        ei, cnt, nullptr, nullptr, nullptr);
    // 3. LN -> h0big (K'=1024 [hi|lo], vectorized) + CSR scan
    k_ln_scan<<<MPAD + 1, 256, 0, stream>>>(hpre, ftb, lng, lnb, h0big, cnt, off);
    // 4. GEMM1 (K'=1024) + fused att-dots + CSR scatter
    k_tgemm<16, true, 2><<<GEMM_BLKS + 313, 512, 0, stream>>>(
        h0big, B1, nullptr, h1b, as1, ad1, aS1, aD1,
        ei, nullptr, off, cursor, csrc);
    // 5. agg1 + BN/ReLU + GEMM2 + att2 (fused, 2-edge-parallel gather)
    k_agg1g2<<<N_NODES, 256, 0, stream>>>(csrc, off, h1b, aS1, aD1,
                                          b1, bnm, bnv, bng, bnb,
                                          W2, as2, ad2, gbuf, aS2, aD2);
    // 6. layer-2 aggregation (fused head-mean + b2)
    k_agg2csr<<<(N_NODES + 3) / 4, 256, 0, stream>>>(csrc, off, gbuf, aS2, aD2, b2, out);
}